// Round 9
// baseline (70.669 us; speedup 1.0000x reference)
//
#include <hip/hip_runtime.h>

// Fused SNN, single main kernel, 1 tile/wave, block-partial spike count.
// MI355X (gfx950). R9: __launch_bounds__(256,8) — occupancy was capped by the
// (256,4) bound (43.7% @ VGPR=44); 8 waves/SIMD fits (8*44=352<512) and grid
// is exactly 8 blocks/CU (2048 blocks / 256 CU).
//
// Per wave = ONE 16-row tile: GEMM1 (conv as banded Toeplitz matmul,
// transposed so C-layout col = batch row) in nt-pairs -> threshold ->
// packed spike B-fragments (+count) -> GEMM2 -> cur1^T in f32 registers ->
// 25-step LIF with W2 as 8-reg uniform A-fragment, 2 MFMAs/step,
// coalesced stores. Spike count: wave reduce -> LDS -> per-block partial
// plain store; finalize_count sums partials (no atomics anywhere).
//
// Contraction-slot bijection (GEMM2/GEMM3 B-side = previous C-layout):
//     k_slot(lk, jj, kt) = 4*lk + (jj&3) + 16*(2*kt + (jj>>2))
// A-side operands are pre-permuted to match by prep_frags.

typedef float    f32x4 __attribute__((ext_vector_type(4)));
typedef short    s16x8 __attribute__((ext_vector_type(8)));

constexpr int L = 187;
constexpr int H = 50;
constexpr int NST = 25;
constexpr float BETA = 0.95f;
constexpr float YTH  = 0.25f;      // y*2 > 0.5  <=>  y > 0.25

constexpr int TTA_SH = 12 * 6 * 64 * 8;   // GEMM1 A fragments
constexpr int W1A_SH = 4 * 6 * 64 * 8;    // GEMM2 A fragments
constexpr int W2A_SH = 2 * 64 * 8;        // GEMM3 A fragments
constexpr int NPART  = 4096;              // per-block count partials (max)

__device__ inline unsigned short f2bf(float f) {
    union { float f; unsigned u; } v; v.f = f;
    return (unsigned short)((v.u + 0x7FFFu + ((v.u >> 16) & 1u)) >> 16);  // RNE
}

// one thread per output short; total = TTA_SH + W1A_SH + W2A_SH = 50176
__global__ void __launch_bounds__(256) prep_frags(
    const float* __restrict__ filt, const float* __restrict__ W1,
    const float* __restrict__ W2,
    unsigned short* __restrict__ TtA, unsigned short* __restrict__ W1A,
    unsigned short* __restrict__ W2A)
{
    int i = blockIdx.x * 256 + threadIdx.x;
    if (i < TTA_SH) {
        // A[l][k]: l = 16*nt + lm, k = 32*kt + 8*lk + jj, val = filt[k-l+24]
        int jj = i & 7, lane = (i >> 3) & 63, kt = (i >> 9) % 6, nt = i / (512 * 6);
        int lm = lane & 15, lk = lane >> 4;
        int l = 16 * nt + lm;
        int k = 32 * kt + 8 * lk + jj;
        int d = k - l + 24;
        unsigned short v = 0;
        if (l < L && k < L && d >= 0 && d < 50) v = f2bf(filt[d]);
        TtA[i] = v;
    } else if (i < TTA_SH + W1A_SH) {
        // A[h][l] permuted: h = 16*mt + lm, l = k_slot(lk,jj,kt)
        int i2 = i - TTA_SH;
        int jj = i2 & 7, lane = (i2 >> 3) & 63, kt = (i2 >> 9) % 6, mt = i2 / (512 * 6);
        int lm = lane & 15, lk = lane >> 4;
        int h = 16 * mt + lm;
        int l = 4 * lk + (jj & 3) + 16 * (2 * kt + (jj >> 2));
        unsigned short v = 0;
        if (h < H && l < L) v = f2bf(W1[h * L + l]);
        W1A[i2] = v;
    } else {
        // A[c][h] permuted: c = lm, h = k_slot(lk,jj,kt)
        int i3 = i - TTA_SH - W1A_SH;
        int jj = i3 & 7, lane = (i3 >> 3) & 63, kt = i3 >> 9;   // kt = 0,1
        int lm = lane & 15, lk = lane >> 4;
        int h = 4 * lk + (jj & 3) + 16 * (2 * kt + (jj >> 2));
        unsigned short v = 0;
        if (lm < 5 && h < H) v = f2bf(W2[lm * H + h]);
        W2A[i3] = v;
    }
}

// ======================= fused main kernel (1 tile / wave) ===================
__global__ void __launch_bounds__(256, 8) snn_fused(
    const float* __restrict__ x,
    const unsigned short* __restrict__ TtA,
    const unsigned short* __restrict__ W1A,
    const unsigned short* __restrict__ W2A,
    float* __restrict__ out, unsigned int* __restrict__ part, int B)
{
    __shared__ unsigned int csh[4];

    const int tid = threadIdx.x;
    const int wid = tid >> 6, lane = tid & 63;
    const int lm = lane & 15, lk = lane >> 4;
    const int row = blockIdx.x * 64 + wid * 16 + lm;

    // xB: B-fragments of GEMM1 (canonical slots)
    s16x8 xB[6];
    {
        const float* __restrict__ xr = x + (size_t)row * L;
        #pragma unroll
        for (int kt = 0; kt < 6; ++kt) {
            const int k0 = 32 * kt + 8 * lk;
            s16x8 v;
            if (k0 + 8 <= L) {
                float t[8];
                __builtin_memcpy(t, xr + k0, 32);
                #pragma unroll
                for (int jj = 0; jj < 8; ++jj) v[jj] = (short)f2bf(t[jj]);
            } else {
                #pragma unroll
                for (int jj = 0; jj < 8; ++jj) {
                    int k = k0 + jj;
                    v[jj] = (short)f2bf((k < L) ? xr[k] : 0.f);
                }
            }
            xB[kt] = v;
        }
    }

    // GEMM1 by nt-pairs: only 2 accumulators live at a time
    int scnt = 0;
    s16x8 spkB[6];
    {
        constexpr int lo[6] = {0, 0, 1, 2, 3, 4};
        constexpr int hi[6] = {1, 2, 3, 4, 5, 5};
        #pragma unroll
        for (int p = 0; p < 6; ++p) {
            f32x4 y0 = (f32x4){0, 0, 0, 0}, y1 = (f32x4){0, 0, 0, 0};
            #pragma unroll
            for (int kt = 0; kt < 6; ++kt) {
                if (kt >= lo[p] && kt <= hi[p]) {
                    s16x8 a0 = *(const s16x8*)(TtA + ((size_t)((2 * p    ) * 6 + kt) * 64 + lane) * 8);
                    s16x8 a1 = *(const s16x8*)(TtA + ((size_t)((2 * p + 1) * 6 + kt) * 64 + lane) * 8);
                    y0 = __builtin_amdgcn_mfma_f32_16x16x32_bf16(a0, xB[kt], y0, 0, 0, 0);
                    y1 = __builtin_amdgcn_mfma_f32_16x16x32_bf16(a1, xB[kt], y1, 0, 0, 0);
                }
            }
            // pack pair -> spkB[p]
            union { unsigned w[4]; s16x8 v; } pk;
            #pragma unroll
            for (int w = 0; w < 4; ++w) {
                float va = (w < 2) ? y0[2 * w]     : y1[2 * (w - 2)];
                float vb = (w < 2) ? y0[2 * w + 1] : y1[2 * (w - 2) + 1];
                bool s0 = va > YTH, s1 = vb > YTH;
                scnt += (int)s0 + (int)s1;
                pk.w[w] = (s0 ? 0x3F80u : 0u) | (s1 ? 0x3F800000u : 0u);
            }
            spkB[p] = pk.v;
        }
    }
    // per-block partial count: wave reduce -> LDS -> one plain store
    #pragma unroll
    for (int off = 32; off; off >>= 1) scnt += __shfl_down(scnt, off);
    if (lane == 0) csh[wid] = (unsigned)scnt;
    __syncthreads();
    if (tid == 0) part[blockIdx.x] = csh[0] + csh[1] + csh[2] + csh[3];

    // GEMM2: cur1^T[h][row] -> f32 registers
    f32x4 cu[4];
    #pragma unroll
    for (int mt = 0; mt < 4; ++mt) cu[mt] = (f32x4){0, 0, 0, 0};
    #pragma unroll
    for (int mt = 0; mt < 4; ++mt)
        #pragma unroll
        for (int kt = 0; kt < 6; ++kt) {
            s16x8 a = *(const s16x8*)(W1A + ((size_t)(mt * 6 + kt) * 64 + lane) * 8);
            cu[mt] = __builtin_amdgcn_mfma_f32_16x16x32_bf16(a, spkB[kt], cu[mt], 0, 0, 0);
        }

    // W2 A-fragments (8 VGPRs)
    s16x8 w2a[2];
    #pragma unroll
    for (int kt = 0; kt < 2; ++kt)
        w2a[kt] = *(const s16x8*)(W2A + ((size_t)kt * 64 + lane) * 8);

    // -------- LIF: 25 steps, all in registers --------
    f32x4 m1[4];
    #pragma unroll
    for (int mt = 0; mt < 4; ++mt) m1[mt] = (f32x4){0, 0, 0, 0};
    f32x4 m2 = (f32x4){0, 0, 0, 0};

    float* __restrict__ po = out + (size_t)row * 5;
    const size_t step = (size_t)B * 5;

    #pragma unroll 1
    for (int t = 0; t < NST; ++t) {
        // m1 update + spk1 pack into permuted B-fragments
        s16x8 s1b[2];
        #pragma unroll
        for (int kt = 0; kt < 2; ++kt) {
            union { unsigned w[4]; s16x8 v; } pk;
            #pragma unroll
            for (int w = 0; w < 4; ++w) {
                const int jj0 = 2 * w, jj1 = 2 * w + 1;
                const int mt0 = 2 * kt + (jj0 >> 2), j0 = jj0 & 3;
                const int mt1 = 2 * kt + (jj1 >> 2), j1 = jj1 & 3;
                float ma = fmaf(BETA, m1[mt0][j0], cu[mt0][j0]);
                float mb = fmaf(BETA, m1[mt1][j1], cu[mt1][j1]);
                bool sa = ma > 1.f, sb = mb > 1.f;
                m1[mt0][j0] = sa ? ma - 1.f : ma;
                m1[mt1][j1] = sb ? mb - 1.f : mb;
                pk.w[w] = (sa ? 0x3F80u : 0u) | (sb ? 0x3F800000u : 0u);
            }
            s1b[kt] = pk.v;
        }
        // cur2^T via 2 MFMAs (accumulator-chained)
        f32x4 c2 = (f32x4){0, 0, 0, 0};
        c2 = __builtin_amdgcn_mfma_f32_16x16x32_bf16(w2a[0], s1b[0], c2, 0, 0, 0);
        c2 = __builtin_amdgcn_mfma_f32_16x16x32_bf16(w2a[1], s1b[1], c2, 0, 0, 0);
        // m2 update + store spikes (lane holds c = 4*lk + j)
        f32x4 sv;
        #pragma unroll
        for (int j = 0; j < 4; ++j) {
            float m = fmaf(BETA, m2[j], c2[j]);
            bool s = m > 1.f;
            m2[j] = s ? m - 1.f : m;
            sv[j] = s ? 1.f : 0.f;
        }
        float* __restrict__ pt = po + (size_t)t * step;
        if (lk == 0) {
            __builtin_memcpy(pt, &sv, 16);        // c = 0..3
        } else if (lk == 1) {
            pt[4] = sv[0];                        // c = 4
        }
    }
}

// sum per-block partials -> out[off] = total * 25   (single block, no atomics)
__global__ void __launch_bounds__(256) finalize_count(
    const unsigned int* __restrict__ part, int n,
    float* __restrict__ out, size_t off)
{
    __shared__ unsigned int sh[4];
    unsigned int s = 0;
    for (int i = threadIdx.x; i < n; i += 256) s += part[i];
    #pragma unroll
    for (int o = 32; o; o >>= 1) s += __shfl_down(s, o);
    if ((threadIdx.x & 63) == 0) sh[threadIdx.x >> 6] = s;
    __syncthreads();
    if (threadIdx.x == 0) {
        unsigned int t = sh[0] + sh[1] + sh[2] + sh[3];
        out[off] = (float)((double)t * 25.0);
    }
}

// ============ fallback: scalar path (only if ws too small) ===================
__global__ void __launch_bounds__(256) snn_fallback(
    const float* __restrict__ x, const float* __restrict__ filt,
    const float* __restrict__ W1, const float* __restrict__ W2,
    float* __restrict__ out, unsigned int* __restrict__ part, int B)
{
    __shared__ unsigned int csh[4];
    const int row = blockIdx.x * 256 + threadIdx.x;
    const bool valid = row < B;
    const int rr = valid ? row : (B - 1);
    const float* __restrict__ xr = x + (size_t)rr * L;
    float w[64], cur1[H];
    #pragma unroll
    for (int h = 0; h < H; ++h) cur1[h] = 0.f;
    int cntv = 0;
    #pragma unroll
    for (int i = 0; i < 64; ++i) w[i] = (i >= 24) ? xr[i - 24] : 0.f;
    #pragma unroll 1
    for (int s = 0; s < 12; ++s) {
        const int l0 = s * 15;
        #pragma unroll
        for (int j = 0; j < 15; ++j) {
            const int l = l0 + j;
            float yv = 0.f;
            #pragma unroll
            for (int k = 0; k < 50; ++k) yv = fmaf(w[j + k], filt[k], yv);
            const bool sb = yv > YTH;
            cntv += sb;
            const float sp = sb ? 1.f : 0.f;
            #pragma unroll
            for (int h = 0; h < H; ++h) cur1[h] = fmaf(sp, W1[h * L + l], cur1[h]);
        }
        #pragma unroll
        for (int i = 0; i < 49; ++i) w[i] = w[i + 15];
        #pragma unroll
        for (int d = 0; d < 15; ++d) {
            const int g = l0 + 40 + d;
            w[49 + d] = (g < L) ? xr[g] : 0.f;
        }
    }
    #pragma unroll
    for (int j = 0; j < 7; ++j) {
        const int l = 180 + j;
        float yv = 0.f;
        #pragma unroll
        for (int k = 0; k < 50; ++k) yv = fmaf(w[j + k], filt[k], yv);
        const bool sb = yv > YTH;
        cntv += sb;
        const float sp = sb ? 1.f : 0.f;
        #pragma unroll
        for (int h = 0; h < H; ++h) cur1[h] = fmaf(sp, W1[h * L + l], cur1[h]);
    }
    int wc = valid ? cntv : 0;
    #pragma unroll
    for (int off = 32; off; off >>= 1) wc += __shfl_down(wc, off);
    if ((threadIdx.x & 63) == 0) csh[threadIdx.x >> 6] = (unsigned)wc;
    __syncthreads();
    if (threadIdx.x == 0) part[blockIdx.x] = csh[0] + csh[1] + csh[2] + csh[3];
    float m1[H], m2[5];
    #pragma unroll
    for (int h = 0; h < H; ++h) m1[h] = 0.f;
    #pragma unroll
    for (int c = 0; c < 5; ++c) m2[c] = 0.f;
    #pragma unroll 1
    for (int t = 0; t < NST; ++t) {
        float c2[5] = {0, 0, 0, 0, 0};
        #pragma unroll
        for (int h = 0; h < H; ++h) {
            float m = fmaf(BETA, m1[h], cur1[h]);
            const float sp = (m > 1.f) ? 1.f : 0.f;
            m1[h] = m - sp;
            #pragma unroll
            for (int c = 0; c < 5; ++c) c2[c] = fmaf(sp, W2[c * H + h], c2[c]);
        }
        float* __restrict__ ot = out + ((size_t)t * B + rr) * 5;
        #pragma unroll
        for (int c = 0; c < 5; ++c) {
            float m = fmaf(BETA, m2[c], c2[c]);
            const float s2 = (m > 1.f) ? 1.f : 0.f;
            m2[c] = m - s2;
            if (valid) ot[c] = s2;
        }
    }
}

extern "C" void kernel_launch(void* const* d_in, const int* in_sizes, int n_in,
                              void* d_out, int out_size, void* d_ws, size_t ws_size,
                              hipStream_t stream)
{
    const float* x    = (const float*)d_in[0];
    const float* filt = (const float*)d_in[1];
    const float* W1   = (const float*)d_in[2];
    const float* W2   = (const float*)d_in[3];
    float* out        = (float*)d_out;
    const int B       = in_sizes[0] / L;          // 131072

    unsigned int* part  = (unsigned int*)d_ws;    // NPART entries
    unsigned short* TtA = (unsigned short*)((char*)d_ws + NPART * 4);
    unsigned short* W1A = TtA + TTA_SH;
    unsigned short* W2A = W1A + W1A_SH;
    const size_t need = (size_t)NPART * 4 + (size_t)(TTA_SH + W1A_SH + W2A_SH) * 2;

    if (ws_size >= need && (B % 64) == 0 && B / 64 <= NPART) {
        const int total = TTA_SH + W1A_SH + W2A_SH;   // 50176
        prep_frags<<<(total + 255) / 256, 256, 0, stream>>>(filt, W1, W2, TtA, W1A, W2A);
        snn_fused<<<B / 64, 256, 0, stream>>>(x, TtA, W1A, W2A, out, part, B);
        finalize_count<<<1, 256, 0, stream>>>(part, B / 64, out, (size_t)NST * B * 5);
    } else {
        snn_fallback<<<(B + 255) / 256, 256, 0, stream>>>(x, filt, W1, W2, out, part, B);
        finalize_count<<<1, 256, 0, stream>>>(part, (B + 255) / 256, out, (size_t)NST * B * 5);
    }
}

// Round 10
// 66.007 us; speedup vs baseline: 1.0706x; 1.0706x over previous
//
#include <hip/hip_runtime.h>

// Fused SNN, single main kernel, 1 tile/wave, block-partial spike count.
// MI355X (gfx950). R10: __launch_bounds__(256,6).
//   R8 (256,4): VGPR 44, no spill, occ 43.7%, 63.6us.
//   R9 (256,8): 64-reg budget -> spill (WRITE +12MB), occ 65.9%, 70.7us. BAD.
//   R10 (256,6): 85-reg budget fits ~76-reg footprint, 6 blocks/CU.
//
// Per wave = ONE 16-row tile: GEMM1 (conv as banded Toeplitz matmul,
// transposed so C-layout col = batch row) in nt-pairs -> threshold ->
// packed spike B-fragments (+count) -> GEMM2 -> cur1^T in f32 registers ->
// 25-step LIF with W2 as 8-reg uniform A-fragment, 2 MFMAs/step,
// coalesced stores. Spike count: wave reduce -> LDS -> per-block partial
// plain store; finalize_count sums partials (no atomics anywhere).
//
// Contraction-slot bijection (GEMM2/GEMM3 B-side = previous C-layout):
//     k_slot(lk, jj, kt) = 4*lk + (jj&3) + 16*(2*kt + (jj>>2))
// A-side operands are pre-permuted to match by prep_frags.

typedef float    f32x4 __attribute__((ext_vector_type(4)));
typedef short    s16x8 __attribute__((ext_vector_type(8)));

constexpr int L = 187;
constexpr int H = 50;
constexpr int NST = 25;
constexpr float BETA = 0.95f;
constexpr float YTH  = 0.25f;      // y*2 > 0.5  <=>  y > 0.25

constexpr int TTA_SH = 12 * 6 * 64 * 8;   // GEMM1 A fragments
constexpr int W1A_SH = 4 * 6 * 64 * 8;    // GEMM2 A fragments
constexpr int W2A_SH = 2 * 64 * 8;        // GEMM3 A fragments
constexpr int NPART  = 4096;              // per-block count partials (max)

__device__ inline unsigned short f2bf(float f) {
    union { float f; unsigned u; } v; v.f = f;
    return (unsigned short)((v.u + 0x7FFFu + ((v.u >> 16) & 1u)) >> 16);  // RNE
}

// one thread per output short; total = TTA_SH + W1A_SH + W2A_SH = 50176
__global__ void __launch_bounds__(256) prep_frags(
    const float* __restrict__ filt, const float* __restrict__ W1,
    const float* __restrict__ W2,
    unsigned short* __restrict__ TtA, unsigned short* __restrict__ W1A,
    unsigned short* __restrict__ W2A)
{
    int i = blockIdx.x * 256 + threadIdx.x;
    if (i < TTA_SH) {
        // A[l][k]: l = 16*nt + lm, k = 32*kt + 8*lk + jj, val = filt[k-l+24]
        int jj = i & 7, lane = (i >> 3) & 63, kt = (i >> 9) % 6, nt = i / (512 * 6);
        int lm = lane & 15, lk = lane >> 4;
        int l = 16 * nt + lm;
        int k = 32 * kt + 8 * lk + jj;
        int d = k - l + 24;
        unsigned short v = 0;
        if (l < L && k < L && d >= 0 && d < 50) v = f2bf(filt[d]);
        TtA[i] = v;
    } else if (i < TTA_SH + W1A_SH) {
        // A[h][l] permuted: h = 16*mt + lm, l = k_slot(lk,jj,kt)
        int i2 = i - TTA_SH;
        int jj = i2 & 7, lane = (i2 >> 3) & 63, kt = (i2 >> 9) % 6, mt = i2 / (512 * 6);
        int lm = lane & 15, lk = lane >> 4;
        int h = 16 * mt + lm;
        int l = 4 * lk + (jj & 3) + 16 * (2 * kt + (jj >> 2));
        unsigned short v = 0;
        if (h < H && l < L) v = f2bf(W1[h * L + l]);
        W1A[i2] = v;
    } else {
        // A[c][h] permuted: c = lm, h = k_slot(lk,jj,kt)
        int i3 = i - TTA_SH - W1A_SH;
        int jj = i3 & 7, lane = (i3 >> 3) & 63, kt = i3 >> 9;   // kt = 0,1
        int lm = lane & 15, lk = lane >> 4;
        int h = 4 * lk + (jj & 3) + 16 * (2 * kt + (jj >> 2));
        unsigned short v = 0;
        if (lm < 5 && h < H) v = f2bf(W2[lm * H + h]);
        W2A[i3] = v;
    }
}

// ======================= fused main kernel (1 tile / wave) ===================
__global__ void __launch_bounds__(256, 6) snn_fused(
    const float* __restrict__ x,
    const unsigned short* __restrict__ TtA,
    const unsigned short* __restrict__ W1A,
    const unsigned short* __restrict__ W2A,
    float* __restrict__ out, unsigned int* __restrict__ part, int B)
{
    __shared__ unsigned int csh[4];

    const int tid = threadIdx.x;
    const int wid = tid >> 6, lane = tid & 63;
    const int lm = lane & 15, lk = lane >> 4;
    const int row = blockIdx.x * 64 + wid * 16 + lm;

    // xB: B-fragments of GEMM1 (canonical slots)
    s16x8 xB[6];
    {
        const float* __restrict__ xr = x + (size_t)row * L;
        #pragma unroll
        for (int kt = 0; kt < 6; ++kt) {
            const int k0 = 32 * kt + 8 * lk;
            s16x8 v;
            if (k0 + 8 <= L) {
                float t[8];
                __builtin_memcpy(t, xr + k0, 32);
                #pragma unroll
                for (int jj = 0; jj < 8; ++jj) v[jj] = (short)f2bf(t[jj]);
            } else {
                #pragma unroll
                for (int jj = 0; jj < 8; ++jj) {
                    int k = k0 + jj;
                    v[jj] = (short)f2bf((k < L) ? xr[k] : 0.f);
                }
            }
            xB[kt] = v;
        }
    }

    // GEMM1 by nt-pairs: only 2 accumulators live at a time
    int scnt = 0;
    s16x8 spkB[6];
    {
        constexpr int lo[6] = {0, 0, 1, 2, 3, 4};
        constexpr int hi[6] = {1, 2, 3, 4, 5, 5};
        #pragma unroll
        for (int p = 0; p < 6; ++p) {
            f32x4 y0 = (f32x4){0, 0, 0, 0}, y1 = (f32x4){0, 0, 0, 0};
            #pragma unroll
            for (int kt = 0; kt < 6; ++kt) {
                if (kt >= lo[p] && kt <= hi[p]) {
                    s16x8 a0 = *(const s16x8*)(TtA + ((size_t)((2 * p    ) * 6 + kt) * 64 + lane) * 8);
                    s16x8 a1 = *(const s16x8*)(TtA + ((size_t)((2 * p + 1) * 6 + kt) * 64 + lane) * 8);
                    y0 = __builtin_amdgcn_mfma_f32_16x16x32_bf16(a0, xB[kt], y0, 0, 0, 0);
                    y1 = __builtin_amdgcn_mfma_f32_16x16x32_bf16(a1, xB[kt], y1, 0, 0, 0);
                }
            }
            // pack pair -> spkB[p]
            union { unsigned w[4]; s16x8 v; } pk;
            #pragma unroll
            for (int w = 0; w < 4; ++w) {
                float va = (w < 2) ? y0[2 * w]     : y1[2 * (w - 2)];
                float vb = (w < 2) ? y0[2 * w + 1] : y1[2 * (w - 2) + 1];
                bool s0 = va > YTH, s1 = vb > YTH;
                scnt += (int)s0 + (int)s1;
                pk.w[w] = (s0 ? 0x3F80u : 0u) | (s1 ? 0x3F800000u : 0u);
            }
            spkB[p] = pk.v;
        }
    }
    // per-block partial count: wave reduce -> LDS -> one plain store
    #pragma unroll
    for (int off = 32; off; off >>= 1) scnt += __shfl_down(scnt, off);
    if (lane == 0) csh[wid] = (unsigned)scnt;
    __syncthreads();
    if (tid == 0) part[blockIdx.x] = csh[0] + csh[1] + csh[2] + csh[3];

    // GEMM2: cur1^T[h][row] -> f32 registers
    f32x4 cu[4];
    #pragma unroll
    for (int mt = 0; mt < 4; ++mt) cu[mt] = (f32x4){0, 0, 0, 0};
    #pragma unroll
    for (int mt = 0; mt < 4; ++mt)
        #pragma unroll
        for (int kt = 0; kt < 6; ++kt) {
            s16x8 a = *(const s16x8*)(W1A + ((size_t)(mt * 6 + kt) * 64 + lane) * 8);
            cu[mt] = __builtin_amdgcn_mfma_f32_16x16x32_bf16(a, spkB[kt], cu[mt], 0, 0, 0);
        }

    // W2 A-fragments (8 VGPRs)
    s16x8 w2a[2];
    #pragma unroll
    for (int kt = 0; kt < 2; ++kt)
        w2a[kt] = *(const s16x8*)(W2A + ((size_t)kt * 64 + lane) * 8);

    // -------- LIF: 25 steps, all in registers --------
    f32x4 m1[4];
    #pragma unroll
    for (int mt = 0; mt < 4; ++mt) m1[mt] = (f32x4){0, 0, 0, 0};
    f32x4 m2 = (f32x4){0, 0, 0, 0};

    float* __restrict__ po = out + (size_t)row * 5;
    const size_t step = (size_t)B * 5;

    #pragma unroll 1
    for (int t = 0; t < NST; ++t) {
        // m1 update + spk1 pack into permuted B-fragments
        s16x8 s1b[2];
        #pragma unroll
        for (int kt = 0; kt < 2; ++kt) {
            union { unsigned w[4]; s16x8 v; } pk;
            #pragma unroll
            for (int w = 0; w < 4; ++w) {
                const int jj0 = 2 * w, jj1 = 2 * w + 1;
                const int mt0 = 2 * kt + (jj0 >> 2), j0 = jj0 & 3;
                const int mt1 = 2 * kt + (jj1 >> 2), j1 = jj1 & 3;
                float ma = fmaf(BETA, m1[mt0][j0], cu[mt0][j0]);
                float mb = fmaf(BETA, m1[mt1][j1], cu[mt1][j1]);
                bool sa = ma > 1.f, sb = mb > 1.f;
                m1[mt0][j0] = sa ? ma - 1.f : ma;
                m1[mt1][j1] = sb ? mb - 1.f : mb;
                pk.w[w] = (sa ? 0x3F80u : 0u) | (sb ? 0x3F800000u : 0u);
            }
            s1b[kt] = pk.v;
        }
        // cur2^T via 2 MFMAs (accumulator-chained)
        f32x4 c2 = (f32x4){0, 0, 0, 0};
        c2 = __builtin_amdgcn_mfma_f32_16x16x32_bf16(w2a[0], s1b[0], c2, 0, 0, 0);
        c2 = __builtin_amdgcn_mfma_f32_16x16x32_bf16(w2a[1], s1b[1], c2, 0, 0, 0);
        // m2 update + store spikes (lane holds c = 4*lk + j)
        f32x4 sv;
        #pragma unroll
        for (int j = 0; j < 4; ++j) {
            float m = fmaf(BETA, m2[j], c2[j]);
            bool s = m > 1.f;
            m2[j] = s ? m - 1.f : m;
            sv[j] = s ? 1.f : 0.f;
        }
        float* __restrict__ pt = po + (size_t)t * step;
        if (lk == 0) {
            __builtin_memcpy(pt, &sv, 16);        // c = 0..3
        } else if (lk == 1) {
            pt[4] = sv[0];                        // c = 4
        }
    }
}

// sum per-block partials -> out[off] = total * 25   (single block, no atomics)
__global__ void __launch_bounds__(256) finalize_count(
    const unsigned int* __restrict__ part, int n,
    float* __restrict__ out, size_t off)
{
    __shared__ unsigned int sh[4];
    unsigned int s = 0;
    for (int i = threadIdx.x; i < n; i += 256) s += part[i];
    #pragma unroll
    for (int o = 32; o; o >>= 1) s += __shfl_down(s, o);
    if ((threadIdx.x & 63) == 0) sh[threadIdx.x >> 6] = s;
    __syncthreads();
    if (threadIdx.x == 0) {
        unsigned int t = sh[0] + sh[1] + sh[2] + sh[3];
        out[off] = (float)((double)t * 25.0);
    }
}

// ============ fallback: scalar path (only if ws too small) ===================
__global__ void __launch_bounds__(256) snn_fallback(
    const float* __restrict__ x, const float* __restrict__ filt,
    const float* __restrict__ W1, const float* __restrict__ W2,
    float* __restrict__ out, unsigned int* __restrict__ part, int B)
{
    __shared__ unsigned int csh[4];
    const int row = blockIdx.x * 256 + threadIdx.x;
    const bool valid = row < B;
    const int rr = valid ? row : (B - 1);
    const float* __restrict__ xr = x + (size_t)rr * L;
    float w[64], cur1[H];
    #pragma unroll
    for (int h = 0; h < H; ++h) cur1[h] = 0.f;
    int cntv = 0;
    #pragma unroll
    for (int i = 0; i < 64; ++i) w[i] = (i >= 24) ? xr[i - 24] : 0.f;
    #pragma unroll 1
    for (int s = 0; s < 12; ++s) {
        const int l0 = s * 15;
        #pragma unroll
        for (int j = 0; j < 15; ++j) {
            const int l = l0 + j;
            float yv = 0.f;
            #pragma unroll
            for (int k = 0; k < 50; ++k) yv = fmaf(w[j + k], filt[k], yv);
            const bool sb = yv > YTH;
            cntv += sb;
            const float sp = sb ? 1.f : 0.f;
            #pragma unroll
            for (int h = 0; h < H; ++h) cur1[h] = fmaf(sp, W1[h * L + l], cur1[h]);
        }
        #pragma unroll
        for (int i = 0; i < 49; ++i) w[i] = w[i + 15];
        #pragma unroll
        for (int d = 0; d < 15; ++d) {
            const int g = l0 + 40 + d;
            w[49 + d] = (g < L) ? xr[g] : 0.f;
        }
    }
    #pragma unroll
    for (int j = 0; j < 7; ++j) {
        const int l = 180 + j;
        float yv = 0.f;
        #pragma unroll
        for (int k = 0; k < 50; ++k) yv = fmaf(w[j + k], filt[k], yv);
        const bool sb = yv > YTH;
        cntv += sb;
        const float sp = sb ? 1.f : 0.f;
        #pragma unroll
        for (int h = 0; h < H; ++h) cur1[h] = fmaf(sp, W1[h * L + l], cur1[h]);
    }
    int wc = valid ? cntv : 0;
    #pragma unroll
    for (int off = 32; off; off >>= 1) wc += __shfl_down(wc, off);
    if ((threadIdx.x & 63) == 0) csh[threadIdx.x >> 6] = (unsigned)wc;
    __syncthreads();
    if (threadIdx.x == 0) part[blockIdx.x] = csh[0] + csh[1] + csh[2] + csh[3];
    float m1[H], m2[5];
    #pragma unroll
    for (int h = 0; h < H; ++h) m1[h] = 0.f;
    #pragma unroll
    for (int c = 0; c < 5; ++c) m2[c] = 0.f;
    #pragma unroll 1
    for (int t = 0; t < NST; ++t) {
        float c2[5] = {0, 0, 0, 0, 0};
        #pragma unroll
        for (int h = 0; h < H; ++h) {
            float m = fmaf(BETA, m1[h], cur1[h]);
            const float sp = (m > 1.f) ? 1.f : 0.f;
            m1[h] = m - sp;
            #pragma unroll
            for (int c = 0; c < 5; ++c) c2[c] = fmaf(sp, W2[c * H + h], c2[c]);
        }
        float* __restrict__ ot = out + ((size_t)t * B + rr) * 5;
        #pragma unroll
        for (int c = 0; c < 5; ++c) {
            float m = fmaf(BETA, m2[c], c2[c]);
            const float s2 = (m > 1.f) ? 1.f : 0.f;
            m2[c] = m - s2;
            if (valid) ot[c] = s2;
        }
    }
}

extern "C" void kernel_launch(void* const* d_in, const int* in_sizes, int n_in,
                              void* d_out, int out_size, void* d_ws, size_t ws_size,
                              hipStream_t stream)
{
    const float* x    = (const float*)d_in[0];
    const float* filt = (const float*)d_in[1];
    const float* W1   = (const float*)d_in[2];
    const float* W2   = (const float*)d_in[3];
    float* out        = (float*)d_out;
    const int B       = in_sizes[0] / L;          // 131072

    unsigned int* part  = (unsigned int*)d_ws;    // NPART entries
    unsigned short* TtA = (unsigned short*)((char*)d_ws + NPART * 4);
    unsigned short* W1A = TtA + TTA_SH;
    unsigned short* W2A = W1A + W1A_SH;
    const size_t need = (size_t)NPART * 4 + (size_t)(TTA_SH + W1A_SH + W2A_SH) * 2;

    if (ws_size >= need && (B % 64) == 0 && B / 64 <= NPART) {
        const int total = TTA_SH + W1A_SH + W2A_SH;   // 50176
        prep_frags<<<(total + 255) / 256, 256, 0, stream>>>(filt, W1, W2, TtA, W1A, W2A);
        snn_fused<<<B / 64, 256, 0, stream>>>(x, TtA, W1A, W2A, out, part, B);
        finalize_count<<<1, 256, 0, stream>>>(part, B / 64, out, (size_t)NST * B * 5);
    } else {
        snn_fallback<<<(B + 255) / 256, 256, 0, stream>>>(x, filt, W1, W2, out, part, B);
        finalize_count<<<1, 256, 0, stream>>>(part, (B + 255) / 256, out, (size_t)NST * B * 5);
    }
}

// Round 11
// 60.459 us; speedup vs baseline: 1.1689x; 1.0918x over previous
//
#include <hip/hip_runtime.h>

// Fused SNN, single main kernel, 1 tile/wave, LDS-resident operands.
// MI355X (gfx950). R11: all shared GEMM operands served from LDS:
//   - Toeplitz A-fragments generated from a 4KB rotated-filter table (8 shifted
//     copies, stride 264 shorts for bank spread): one ds_read_b128 per frag.
//   - W1A (24KB) + W2A (2KB) staged per block via linear uint4 copies.
// Replaces ~475MB of per-wave global re-reads of wave-invariant data.
// Phantom conv rows l>=187 (previously zeroed in TtA) are count-masked only;
// W1A zeros those columns so cur1 is unaffected.
//
// Per wave = ONE 16-row tile: GEMM1 (banded Toeplitz matmul, transposed so
// C-layout col = batch row) in nt-pairs -> threshold -> packed spike
// B-fragments (+count) -> GEMM2 -> cur1^T in f32 registers -> 25-step LIF
// with W2 as 8-reg uniform A-fragment, 2 MFMAs/step, coalesced stores.
// Spike count: wave reduce -> LDS -> per-block partial store; finalize sums.
//
// Contraction-slot bijection (GEMM2/GEMM3 B-side = previous C-layout):
//     k_slot(lk, jj, kt) = 4*lk + (jj&3) + 16*(2*kt + (jj>>2))

typedef float    f32x4 __attribute__((ext_vector_type(4)));
typedef short    s16x8 __attribute__((ext_vector_type(8)));

constexpr int L = 187;
constexpr int H = 50;
constexpr int NST = 25;
constexpr float BETA = 0.95f;
constexpr float YTH  = 0.25f;      // y*2 > 0.5  <=>  y > 0.25

constexpr int FT_STR = 264;               // ftab copy stride (shorts), 16B-mult
constexpr int FT_SH  = 8 * FT_STR;        // 2112 shorts = 4224 B
constexpr int W1A_SH = 4 * 6 * 64 * 8;    // 12288 shorts = 24 KB
constexpr int W2A_SH = 2 * 64 * 8;        // 1024 shorts = 2 KB
constexpr int NPART  = 4096;              // per-block count partials (max)

__device__ inline unsigned short f2bf(float f) {
    union { float f; unsigned u; } v; v.f = f;
    return (unsigned short)((v.u + 0x7FFFu + ((v.u >> 16) & 1u)) >> 16);  // RNE
}

// prep: ftab[r][m] = filt[m + r - 48] (0-padded), r<8, m<264, pre-strided;
// then W1A, W2A permuted fragments (same as before). Total 15424 shorts.
__global__ void __launch_bounds__(256) prep_frags(
    const float* __restrict__ filt, const float* __restrict__ W1,
    const float* __restrict__ W2, unsigned short* __restrict__ frags)
{
    int i = blockIdx.x * 256 + threadIdx.x;
    if (i < FT_SH) {
        int r = i / FT_STR, m = i - r * FT_STR;
        int idx = m + r - 48;
        frags[i] = (idx >= 0 && idx < 50) ? f2bf(filt[idx]) : (unsigned short)0;
    } else if (i < FT_SH + W1A_SH) {
        // A[h][l] permuted: h = 16*mt + lm, l = k_slot(lk,jj,kt)
        int i2 = i - FT_SH;
        int jj = i2 & 7, lane = (i2 >> 3) & 63, kt = (i2 >> 9) % 6, mt = i2 / (512 * 6);
        int lm = lane & 15, lk = lane >> 4;
        int h = 16 * mt + lm;
        int l = 4 * lk + (jj & 3) + 16 * (2 * kt + (jj >> 2));
        unsigned short v = 0;
        if (h < H && l < L) v = f2bf(W1[h * L + l]);
        frags[i] = v;
    } else if (i < FT_SH + W1A_SH + W2A_SH) {
        // A[c][h] permuted: c = lm, h = k_slot(lk,jj,kt)
        int i3 = i - FT_SH - W1A_SH;
        int jj = i3 & 7, lane = (i3 >> 3) & 63, kt = i3 >> 9;   // kt = 0,1
        int lm = lane & 15, lk = lane >> 4;
        int h = 4 * lk + (jj & 3) + 16 * (2 * kt + (jj >> 2));
        unsigned short v = 0;
        if (lm < 5 && h < H) v = f2bf(W2[lm * H + h]);
        frags[i] = v;
    }
}

// ======================= fused main kernel (1 tile / wave) ===================
__global__ void __launch_bounds__(256, 4) snn_fused(
    const float* __restrict__ x,
    const unsigned short* __restrict__ frags,
    float* __restrict__ out, unsigned int* __restrict__ part, int B)
{
    __shared__ __align__(16) unsigned short ftabL[FT_SH];
    __shared__ __align__(16) unsigned short W1L[W1A_SH];
    __shared__ __align__(16) unsigned short W2L[W2A_SH];
    __shared__ unsigned int csh[4];

    const int tid = threadIdx.x;
    const int wid = tid >> 6, lane = tid & 63;
    const int lm = lane & 15, lk = lane >> 4;
    const int row = blockIdx.x * 64 + wid * 16 + lm;

    // ---- stage wave-invariant operands to LDS (linear uint4 copies) ----
    {
        const uint4* g = (const uint4*)frags;     // 264 + 1536 + 128 chunks
        uint4* sF = (uint4*)ftabL;
        uint4* s1 = (uint4*)W1L;
        uint4* s2 = (uint4*)W2L;
        #pragma unroll 2
        for (int i = tid; i < 264; i += 256) sF[i] = g[i];
        #pragma unroll
        for (int i = tid; i < 1536; i += 256) s1[i] = g[264 + i];
        if (tid < 128) s2[tid] = g[264 + 1536 + tid];
    }
    __syncthreads();

    // xB: B-fragments of GEMM1 (canonical slots)
    s16x8 xB[6];
    {
        const float* __restrict__ xr = x + (size_t)row * L;
        #pragma unroll
        for (int kt = 0; kt < 6; ++kt) {
            const int k0 = 32 * kt + 8 * lk;
            s16x8 v;
            if (k0 + 8 <= L) {
                float t[8];
                __builtin_memcpy(t, xr + k0, 32);
                #pragma unroll
                for (int jj = 0; jj < 8; ++jj) v[jj] = (short)f2bf(t[jj]);
            } else {
                #pragma unroll
                for (int jj = 0; jj < 8; ++jj) {
                    int k = k0 + jj;
                    v[jj] = (short)f2bf((k < L) ? xr[k] : 0.f);
                }
            }
            xB[kt] = v;
        }
    }

    // GEMM1 by nt-pairs; A-fragments from the rotated filter table:
    // lane needs filt[d0 .. d0+7], d0 = 32kt + 8lk - 16nt - lm + 24.
    // D0 = d0+48; frag = ftabL[(D0&7)*FT_STR + (D0>>3)*8 .. +7].
    const int dl = 8 * lk - lm + 72;              // +24 (toeplitz) +48 (table)
    int scnt = 0;
    s16x8 spkB[6];
    {
        constexpr int lo[6] = {0, 0, 1, 2, 3, 4};
        constexpr int hi[6] = {1, 2, 3, 4, 5, 5};
        #pragma unroll
        for (int p = 0; p < 6; ++p) {
            f32x4 y0 = (f32x4){0, 0, 0, 0}, y1 = (f32x4){0, 0, 0, 0};
            #pragma unroll
            for (int kt = 0; kt < 6; ++kt) {
                if (kt >= lo[p] && kt <= hi[p]) {
                    const int D0a = dl + 32 * kt - 32 * p;      // nt = 2p
                    const int D0b = D0a - 16;                   // nt = 2p+1
                    s16x8 a0 = *(const s16x8*)&ftabL[(D0a & 7) * FT_STR + (D0a & ~7)];
                    s16x8 a1 = *(const s16x8*)&ftabL[(D0b & 7) * FT_STR + (D0b & ~7)];
                    y0 = __builtin_amdgcn_mfma_f32_16x16x32_bf16(a0, xB[kt], y0, 0, 0, 0);
                    y1 = __builtin_amdgcn_mfma_f32_16x16x32_bf16(a1, xB[kt], y1, 0, 0, 0);
                }
            }
            // pack pair -> spkB[p]; count-mask phantom rows l>=187 (p=5, y1)
            union { unsigned w[4]; s16x8 v; } pk;
            #pragma unroll
            for (int w = 0; w < 4; ++w) {
                float va = (w < 2) ? y0[2 * w]     : y1[2 * (w - 2)];
                float vb = (w < 2) ? y0[2 * w + 1] : y1[2 * (w - 2) + 1];
                bool s0 = va > YTH, s1 = vb > YTH;
                bool ok0 = true, ok1 = true;
                if (p == 5 && w >= 2) {           // y1 rows: l = 176 + 4lk + j
                    ok0 = (4 * lk + 2 * (w - 2))     < 11;
                    ok1 = (4 * lk + 2 * (w - 2) + 1) < 11;
                }
                scnt += (int)(s0 & ok0) + (int)(s1 & ok1);
                pk.w[w] = (s0 ? 0x3F80u : 0u) | (s1 ? 0x3F800000u : 0u);
            }
            spkB[p] = pk.v;
        }
    }
    // per-block partial count: wave reduce -> LDS -> one plain store
    #pragma unroll
    for (int off = 32; off; off >>= 1) scnt += __shfl_down(scnt, off);
    if (lane == 0) csh[wid] = (unsigned)scnt;
    __syncthreads();
    if (tid == 0) part[blockIdx.x] = csh[0] + csh[1] + csh[2] + csh[3];

    // GEMM2: cur1^T[h][row] -> f32 registers (A from LDS)
    f32x4 cu[4];
    #pragma unroll
    for (int mt = 0; mt < 4; ++mt) cu[mt] = (f32x4){0, 0, 0, 0};
    #pragma unroll
    for (int mt = 0; mt < 4; ++mt)
        #pragma unroll
        for (int kt = 0; kt < 6; ++kt) {
            s16x8 a = *(const s16x8*)&W1L[((mt * 6 + kt) * 64 + lane) * 8];
            cu[mt] = __builtin_amdgcn_mfma_f32_16x16x32_bf16(a, spkB[kt], cu[mt], 0, 0, 0);
        }

    // W2 A-fragments (8 VGPRs, from LDS)
    s16x8 w2a[2];
    #pragma unroll
    for (int kt = 0; kt < 2; ++kt)
        w2a[kt] = *(const s16x8*)&W2L[(kt * 64 + lane) * 8];

    // -------- LIF: 25 steps, all in registers --------
    f32x4 m1[4];
    #pragma unroll
    for (int mt = 0; mt < 4; ++mt) m1[mt] = (f32x4){0, 0, 0, 0};
    f32x4 m2 = (f32x4){0, 0, 0, 0};

    float* __restrict__ po = out + (size_t)row * 5;
    const size_t step = (size_t)B * 5;

    #pragma unroll 1
    for (int t = 0; t < NST; ++t) {
        // m1 update + spk1 pack into permuted B-fragments
        s16x8 s1b[2];
        #pragma unroll
        for (int kt = 0; kt < 2; ++kt) {
            union { unsigned w[4]; s16x8 v; } pk;
            #pragma unroll
            for (int w = 0; w < 4; ++w) {
                const int jj0 = 2 * w, jj1 = 2 * w + 1;
                const int mt0 = 2 * kt + (jj0 >> 2), j0 = jj0 & 3;
                const int mt1 = 2 * kt + (jj1 >> 2), j1 = jj1 & 3;
                float ma = fmaf(BETA, m1[mt0][j0], cu[mt0][j0]);
                float mb = fmaf(BETA, m1[mt1][j1], cu[mt1][j1]);
                bool sa = ma > 1.f, sb = mb > 1.f;
                m1[mt0][j0] = sa ? ma - 1.f : ma;
                m1[mt1][j1] = sb ? mb - 1.f : mb;
                pk.w[w] = (sa ? 0x3F80u : 0u) | (sb ? 0x3F800000u : 0u);
            }
            s1b[kt] = pk.v;
        }
        // cur2^T via 2 MFMAs (accumulator-chained)
        f32x4 c2 = (f32x4){0, 0, 0, 0};
        c2 = __builtin_amdgcn_mfma_f32_16x16x32_bf16(w2a[0], s1b[0], c2, 0, 0, 0);
        c2 = __builtin_amdgcn_mfma_f32_16x16x32_bf16(w2a[1], s1b[1], c2, 0, 0, 0);
        // m2 update + store spikes (lane holds c = 4*lk + j)
        f32x4 sv;
        #pragma unroll
        for (int j = 0; j < 4; ++j) {
            float m = fmaf(BETA, m2[j], c2[j]);
            bool s = m > 1.f;
            m2[j] = s ? m - 1.f : m;
            sv[j] = s ? 1.f : 0.f;
        }
        float* __restrict__ pt = po + (size_t)t * step;
        if (lk == 0) {
            __builtin_memcpy(pt, &sv, 16);        // c = 0..3
        } else if (lk == 1) {
            pt[4] = sv[0];                        // c = 4
        }
    }
}

// sum per-block partials -> out[off] = total * 25   (single block, no atomics)
__global__ void __launch_bounds__(256) finalize_count(
    const unsigned int* __restrict__ part, int n,
    float* __restrict__ out, size_t off)
{
    __shared__ unsigned int sh[4];
    unsigned int s = 0;
    for (int i = threadIdx.x; i < n; i += 256) s += part[i];
    #pragma unroll
    for (int o = 32; o; o >>= 1) s += __shfl_down(s, o);
    if ((threadIdx.x & 63) == 0) sh[threadIdx.x >> 6] = s;
    __syncthreads();
    if (threadIdx.x == 0) {
        unsigned int t = sh[0] + sh[1] + sh[2] + sh[3];
        out[off] = (float)((double)t * 25.0);
    }
}

// ============ fallback: scalar path (only if ws too small) ===================
__global__ void __launch_bounds__(256) snn_fallback(
    const float* __restrict__ x, const float* __restrict__ filt,
    const float* __restrict__ W1, const float* __restrict__ W2,
    float* __restrict__ out, unsigned int* __restrict__ part, int B)
{
    __shared__ unsigned int csh[4];
    const int row = blockIdx.x * 256 + threadIdx.x;
    const bool valid = row < B;
    const int rr = valid ? row : (B - 1);
    const float* __restrict__ xr = x + (size_t)rr * L;
    float w[64], cur1[H];
    #pragma unroll
    for (int h = 0; h < H; ++h) cur1[h] = 0.f;
    int cntv = 0;
    #pragma unroll
    for (int i = 0; i < 64; ++i) w[i] = (i >= 24) ? xr[i - 24] : 0.f;
    #pragma unroll 1
    for (int s = 0; s < 12; ++s) {
        const int l0 = s * 15;
        #pragma unroll
        for (int j = 0; j < 15; ++j) {
            const int l = l0 + j;
            float yv = 0.f;
            #pragma unroll
            for (int k = 0; k < 50; ++k) yv = fmaf(w[j + k], filt[k], yv);
            const bool sb = yv > YTH;
            cntv += sb;
            const float sp = sb ? 1.f : 0.f;
            #pragma unroll
            for (int h = 0; h < H; ++h) cur1[h] = fmaf(sp, W1[h * L + l], cur1[h]);
        }
        #pragma unroll
        for (int i = 0; i < 49; ++i) w[i] = w[i + 15];
        #pragma unroll
        for (int d = 0; d < 15; ++d) {
            const int g = l0 + 40 + d;
            w[49 + d] = (g < L) ? xr[g] : 0.f;
        }
    }
    #pragma unroll
    for (int j = 0; j < 7; ++j) {
        const int l = 180 + j;
        float yv = 0.f;
        #pragma unroll
        for (int k = 0; k < 50; ++k) yv = fmaf(w[j + k], filt[k], yv);
        const bool sb = yv > YTH;
        cntv += sb;
        const float sp = sb ? 1.f : 0.f;
        #pragma unroll
        for (int h = 0; h < H; ++h) cur1[h] = fmaf(sp, W1[h * L + l], cur1[h]);
    }
    int wc = valid ? cntv : 0;
    #pragma unroll
    for (int off = 32; off; off >>= 1) wc += __shfl_down(wc, off);
    if ((threadIdx.x & 63) == 0) csh[threadIdx.x >> 6] = (unsigned)wc;
    __syncthreads();
    if (threadIdx.x == 0) part[blockIdx.x] = csh[0] + csh[1] + csh[2] + csh[3];
    float m1[H], m2[5];
    #pragma unroll
    for (int h = 0; h < H; ++h) m1[h] = 0.f;
    #pragma unroll
    for (int c = 0; c < 5; ++c) m2[c] = 0.f;
    #pragma unroll 1
    for (int t = 0; t < NST; ++t) {
        float c2[5] = {0, 0, 0, 0, 0};
        #pragma unroll
        for (int h = 0; h < H; ++h) {
            float m = fmaf(BETA, m1[h], cur1[h]);
            const float sp = (m > 1.f) ? 1.f : 0.f;
            m1[h] = m - sp;
            #pragma unroll
            for (int c = 0; c < 5; ++c) c2[c] = fmaf(sp, W2[c * H + h], c2[c]);
        }
        float* __restrict__ ot = out + ((size_t)t * B + rr) * 5;
        #pragma unroll
        for (int c = 0; c < 5; ++c) {
            float m = fmaf(BETA, m2[c], c2[c]);
            const float s2 = (m > 1.f) ? 1.f : 0.f;
            m2[c] = m - s2;
            if (valid) ot[c] = s2;
        }
    }
}

extern "C" void kernel_launch(void* const* d_in, const int* in_sizes, int n_in,
                              void* d_out, int out_size, void* d_ws, size_t ws_size,
                              hipStream_t stream)
{
    const float* x    = (const float*)d_in[0];
    const float* filt = (const float*)d_in[1];
    const float* W1   = (const float*)d_in[2];
    const float* W2   = (const float*)d_in[3];
    float* out        = (float*)d_out;
    const int B       = in_sizes[0] / L;          // 131072

    unsigned int* part    = (unsigned int*)d_ws;                   // NPART u32
    unsigned short* frags = (unsigned short*)((char*)d_ws + NPART * 4);
    const int total_sh    = FT_SH + W1A_SH + W2A_SH;               // 15424
    const size_t need     = (size_t)NPART * 4 + (size_t)total_sh * 2;

    if (ws_size >= need && (B % 64) == 0 && B / 64 <= NPART) {
        prep_frags<<<(total_sh + 255) / 256, 256, 0, stream>>>(filt, W1, W2, frags);
        snn_fused<<<B / 64, 256, 0, stream>>>(x, frags, out, part, B);
        finalize_count<<<1, 256, 0, stream>>>(part, B / 64, out, (size_t)NST * B * 5);
    } else {
        snn_fallback<<<(B + 255) / 256, 256, 0, stream>>>(x, filt, W1, W2, out, part, B);
        finalize_count<<<1, 256, 0, stream>>>(part, (B + 255) / 256, out, (size_t)NST * B * 5);
    }
}

// Round 12
// 55.834 us; speedup vs baseline: 1.2657x; 1.0828x over previous
//
#include <hip/hip_runtime.h>

// Fused SNN, single main kernel, 1 tile/wave, LDS-resident operands.
// MI355X (gfx950). R12: VALU diet in the LIF loop:
//   - f32x2 packed math (v_pk_fma_f32 / v_pk_add_f32 via <2 x float> ops);
//     s1b pair layout == m1[mt] lo/hi halves, so packing is free.
//   - v_perm_b32 packs two spikes (bf16(1.0) = hi half of f32(1.0) bits).
//   - m1[3] hi pair is phantom (h>=50 for all lanes): constant 0, not computed.
//   - GEMM1 spike count via ballot+popc (SALU) instead of per-lane addc+shfl.
//
// Per wave = ONE 16-row tile: GEMM1 (banded Toeplitz matmul from a rotated
// filter table in LDS, transposed so C-layout col = batch row) in nt-pairs ->
// threshold -> packed spike B-fragments (+count) -> GEMM2 (W1 frags in LDS)
// -> cur1^T in f32 registers -> 25-step LIF, W2 8-reg uniform A-fragment,
// 2 MFMAs/step, coalesced stores. Count: per-block partial; finalize sums.
//
// Contraction-slot bijection (GEMM2/GEMM3 B-side = previous C-layout):
//     k_slot(lk, jj, kt) = 4*lk + (jj&3) + 16*(2*kt + (jj>>2))

typedef float    f32x4 __attribute__((ext_vector_type(4)));
typedef float    f32x2 __attribute__((ext_vector_type(2)));
typedef short    s16x8 __attribute__((ext_vector_type(8)));

constexpr int L = 187;
constexpr int H = 50;
constexpr int NST = 25;
constexpr float BETA = 0.95f;
constexpr float YTH  = 0.25f;      // y*2 > 0.5  <=>  y > 0.25

constexpr int FT_STR = 264;               // ftab copy stride (shorts), 16B-mult
constexpr int FT_SH  = 8 * FT_STR;        // 2112 shorts = 4224 B
constexpr int W1A_SH = 4 * 6 * 64 * 8;    // 12288 shorts = 24 KB
constexpr int W2A_SH = 2 * 64 * 8;        // 1024 shorts = 2 KB
constexpr int NPART  = 4096;              // per-block count partials (max)

__device__ inline unsigned short f2bf(float f) {
    union { float f; unsigned u; } v; v.f = f;
    return (unsigned short)((v.u + 0x7FFFu + ((v.u >> 16) & 1u)) >> 16);  // RNE
}

// prep: ftab[r][m] = filt[m + r - 48] (0-padded), r<8, m<264, pre-strided;
// then W1A, W2A permuted fragments. Total 15424 shorts.
__global__ void __launch_bounds__(256) prep_frags(
    const float* __restrict__ filt, const float* __restrict__ W1,
    const float* __restrict__ W2, unsigned short* __restrict__ frags)
{
    int i = blockIdx.x * 256 + threadIdx.x;
    if (i < FT_SH) {
        int r = i / FT_STR, m = i - r * FT_STR;
        int idx = m + r - 48;
        frags[i] = (idx >= 0 && idx < 50) ? f2bf(filt[idx]) : (unsigned short)0;
    } else if (i < FT_SH + W1A_SH) {
        // A[h][l] permuted: h = 16*mt + lm, l = k_slot(lk,jj,kt)
        int i2 = i - FT_SH;
        int jj = i2 & 7, lane = (i2 >> 3) & 63, kt = (i2 >> 9) % 6, mt = i2 / (512 * 6);
        int lm = lane & 15, lk = lane >> 4;
        int h = 16 * mt + lm;
        int l = 4 * lk + (jj & 3) + 16 * (2 * kt + (jj >> 2));
        unsigned short v = 0;
        if (h < H && l < L) v = f2bf(W1[h * L + l]);
        frags[i] = v;
    } else if (i < FT_SH + W1A_SH + W2A_SH) {
        // A[c][h] permuted: c = lm, h = k_slot(lk,jj,kt)
        int i3 = i - FT_SH - W1A_SH;
        int jj = i3 & 7, lane = (i3 >> 3) & 63, kt = i3 >> 9;   // kt = 0,1
        int lm = lane & 15, lk = lane >> 4;
        int h = 4 * lk + (jj & 3) + 16 * (2 * kt + (jj >> 2));
        unsigned short v = 0;
        if (lm < 5 && h < H) v = f2bf(W2[lm * H + h]);
        frags[i] = v;
    }
}

// ======================= fused main kernel (1 tile / wave) ===================
__global__ void __launch_bounds__(256, 4) snn_fused(
    const float* __restrict__ x,
    const unsigned short* __restrict__ frags,
    float* __restrict__ out, unsigned int* __restrict__ part, int B)
{
    __shared__ __align__(16) unsigned short ftabL[FT_SH];
    __shared__ __align__(16) unsigned short W1L[W1A_SH];
    __shared__ __align__(16) unsigned short W2L[W2A_SH];
    __shared__ unsigned int csh[4];

    const int tid = threadIdx.x;
    const int wid = tid >> 6, lane = tid & 63;
    const int lm = lane & 15, lk = lane >> 4;
    const int row = blockIdx.x * 64 + wid * 16 + lm;

    // ---- stage wave-invariant operands to LDS (linear uint4 copies) ----
    {
        const uint4* g = (const uint4*)frags;     // 264 + 1536 + 128 chunks
        uint4* sF = (uint4*)ftabL;
        uint4* s1 = (uint4*)W1L;
        uint4* s2 = (uint4*)W2L;
        #pragma unroll 2
        for (int i = tid; i < 264; i += 256) sF[i] = g[i];
        #pragma unroll
        for (int i = tid; i < 1536; i += 256) s1[i] = g[264 + i];
        if (tid < 128) s2[tid] = g[264 + 1536 + tid];
    }
    __syncthreads();

    // xB: B-fragments of GEMM1 (canonical slots)
    s16x8 xB[6];
    {
        const float* __restrict__ xr = x + (size_t)row * L;
        #pragma unroll
        for (int kt = 0; kt < 6; ++kt) {
            const int k0 = 32 * kt + 8 * lk;
            s16x8 v;
            if (k0 + 8 <= L) {
                float t[8];
                __builtin_memcpy(t, xr + k0, 32);
                #pragma unroll
                for (int jj = 0; jj < 8; ++jj) v[jj] = (short)f2bf(t[jj]);
            } else {
                #pragma unroll
                for (int jj = 0; jj < 8; ++jj) {
                    int k = k0 + jj;
                    v[jj] = (short)f2bf((k < L) ? xr[k] : 0.f);
                }
            }
            xB[kt] = v;
        }
    }

    // GEMM1 by nt-pairs; A-fragments from the rotated filter table:
    // lane needs filt[d0 .. d0+7], d0 = 32kt + 8lk - 16nt - lm + 24.
    // D0 = d0+48; frag = ftabL[(D0&7)*FT_STR + (D0&~7) .. +7].
    const int dl = 8 * lk - lm + 72;              // +24 (toeplitz) +48 (table)
    unsigned int scnt = 0;                        // wave-uniform (ballot count)
    s16x8 spkB[6];
    {
        constexpr int lo[6] = {0, 0, 1, 2, 3, 4};
        constexpr int hi[6] = {1, 2, 3, 4, 5, 5};
        #pragma unroll
        for (int p = 0; p < 6; ++p) {
            f32x4 y0 = (f32x4){0, 0, 0, 0}, y1 = (f32x4){0, 0, 0, 0};
            #pragma unroll
            for (int kt = 0; kt < 6; ++kt) {
                if (kt >= lo[p] && kt <= hi[p]) {
                    const int D0a = dl + 32 * kt - 32 * p;      // nt = 2p
                    const int D0b = D0a - 16;                   // nt = 2p+1
                    s16x8 a0 = *(const s16x8*)&ftabL[(D0a & 7) * FT_STR + (D0a & ~7)];
                    s16x8 a1 = *(const s16x8*)&ftabL[(D0b & 7) * FT_STR + (D0b & ~7)];
                    y0 = __builtin_amdgcn_mfma_f32_16x16x32_bf16(a0, xB[kt], y0, 0, 0, 0);
                    y1 = __builtin_amdgcn_mfma_f32_16x16x32_bf16(a1, xB[kt], y1, 0, 0, 0);
                }
            }
            // pack pair -> spkB[p]; count via ballot (SALU); count-mask
            // phantom rows l>=187 (p=5, y1 side)
            union { unsigned w[4]; s16x8 v; } pk;
            #pragma unroll
            for (int w = 0; w < 4; ++w) {
                float va = (w < 2) ? y0[2 * w]     : y1[2 * (w - 2)];
                float vb = (w < 2) ? y0[2 * w + 1] : y1[2 * (w - 2) + 1];
                bool s0 = va > YTH, s1 = vb > YTH;
                bool c0 = s0, c1 = s1;
                if (p == 5 && w >= 2) {           // y1 rows: l = 176 + 4lk + j
                    c0 = s0 && ((4 * lk + 2 * (w - 2))     < 11);
                    c1 = s1 && ((4 * lk + 2 * (w - 2) + 1) < 11);
                }
                scnt += (unsigned)__popcll(__ballot(c0));
                scnt += (unsigned)__popcll(__ballot(c1));
                pk.w[w] = (s0 ? 0x3F80u : 0u) | (s1 ? 0x3F800000u : 0u);
            }
            spkB[p] = pk.v;
        }
    }
    // per-block partial count: scnt already wave-uniform
    if (lane == 0) csh[wid] = scnt;
    __syncthreads();
    if (tid == 0) part[blockIdx.x] = csh[0] + csh[1] + csh[2] + csh[3];

    // GEMM2: cur1^T[h][row] -> f32 registers (A from LDS)
    f32x4 cu[4];
    #pragma unroll
    for (int mt = 0; mt < 4; ++mt) cu[mt] = (f32x4){0, 0, 0, 0};
    #pragma unroll
    for (int mt = 0; mt < 4; ++mt)
        #pragma unroll
        for (int kt = 0; kt < 6; ++kt) {
            s16x8 a = *(const s16x8*)&W1L[((mt * 6 + kt) * 64 + lane) * 8];
            cu[mt] = __builtin_amdgcn_mfma_f32_16x16x32_bf16(a, spkB[kt], cu[mt], 0, 0, 0);
        }

    // W2 A-fragments (8 VGPRs, from LDS)
    s16x8 w2a[2];
    #pragma unroll
    for (int kt = 0; kt < 2; ++kt)
        w2a[kt] = *(const s16x8*)&W2L[(kt * 64 + lane) * 8];

    // -------- LIF: 25 steps, packed-f32 math --------
    // state as f32x2 pairs; pair (mt,hf) == s1b slot pw[2*mt+hf].
    f32x2 cup[4][2], m1p[4][2];
    #pragma unroll
    for (int mt = 0; mt < 4; ++mt) {
        cup[mt][0] = (f32x2){cu[mt][0], cu[mt][1]};
        cup[mt][1] = (f32x2){cu[mt][2], cu[mt][3]};
        m1p[mt][0] = (f32x2){0.f, 0.f};
        m1p[mt][1] = (f32x2){0.f, 0.f};
    }
    f32x4 m2 = (f32x4){0, 0, 0, 0};
    const f32x2 B2 = (f32x2){BETA, BETA};
    const f32x4 B4 = (f32x4){BETA, BETA, BETA, BETA};

    float* __restrict__ po = out + (size_t)row * 5;
    const size_t step = (size_t)B * 5;

    #pragma unroll 1
    for (int t = 0; t < NST; ++t) {
        unsigned pw[8];
        pw[7] = 0u;                                // mt3 hi: h>=50 for all lanes
        #pragma unroll
        for (int mt = 0; mt < 4; ++mt) {
            #pragma unroll
            for (int hf = 0; hf < 2; ++hf) {
                if (mt == 3 && hf == 1) continue;  // phantom pair
                f32x2 m = B2 * m1p[mt][hf] + cup[mt][hf];     // v_pk_fma_f32
                float s0 = (m[0] > 1.f) ? 1.f : 0.f;
                float s1 = (m[1] > 1.f) ? 1.f : 0.f;
                pw[2 * mt + hf] = __builtin_amdgcn_perm(
                    __float_as_uint(s1), __float_as_uint(s0), 0x07060302u);
                m1p[mt][hf] = m - (f32x2){s0, s1};            // v_pk_add_f32
            }
        }
        union { unsigned w[4]; s16x8 v; } u0, u1;
        u0.w[0] = pw[0]; u0.w[1] = pw[1]; u0.w[2] = pw[2]; u0.w[3] = pw[3];
        u1.w[0] = pw[4]; u1.w[1] = pw[5]; u1.w[2] = pw[6]; u1.w[3] = pw[7];
        // cur2^T via 2 MFMAs (accumulator-chained)
        f32x4 c2 = (f32x4){0, 0, 0, 0};
        c2 = __builtin_amdgcn_mfma_f32_16x16x32_bf16(w2a[0], u0.v, c2, 0, 0, 0);
        c2 = __builtin_amdgcn_mfma_f32_16x16x32_bf16(w2a[1], u1.v, c2, 0, 0, 0);
        // m2 update + store spikes (lane holds c = 4*lk + j)
        f32x4 mm = B4 * m2 + c2;                              // 2x v_pk_fma
        f32x4 sv;
        #pragma unroll
        for (int j = 0; j < 4; ++j) sv[j] = (mm[j] > 1.f) ? 1.f : 0.f;
        m2 = mm - sv;                                         // 2x v_pk_add
        float* __restrict__ pt = po + (size_t)t * step;
        if (lk == 0) {
            __builtin_memcpy(pt, &sv, 16);        // c = 0..3
        } else if (lk == 1) {
            pt[4] = sv[0];                        // c = 4
        }
    }
}

// sum per-block partials -> out[off] = total * 25   (single block, no atomics)
__global__ void __launch_bounds__(256) finalize_count(
    const unsigned int* __restrict__ part, int n,
    float* __restrict__ out, size_t off)
{
    __shared__ unsigned int sh[4];
    unsigned int s = 0;
    for (int i = threadIdx.x; i < n; i += 256) s += part[i];
    #pragma unroll
    for (int o = 32; o; o >>= 1) s += __shfl_down(s, o);
    if ((threadIdx.x & 63) == 0) sh[threadIdx.x >> 6] = s;
    __syncthreads();
    if (threadIdx.x == 0) {
        unsigned int t = sh[0] + sh[1] + sh[2] + sh[3];
        out[off] = (float)((double)t * 25.0);
    }
}

// ============ fallback: scalar path (only if ws too small) ===================
__global__ void __launch_bounds__(256) snn_fallback(
    const float* __restrict__ x, const float* __restrict__ filt,
    const float* __restrict__ W1, const float* __restrict__ W2,
    float* __restrict__ out, unsigned int* __restrict__ part, int B)
{
    __shared__ unsigned int csh[4];
    const int row = blockIdx.x * 256 + threadIdx.x;
    const bool valid = row < B;
    const int rr = valid ? row : (B - 1);
    const float* __restrict__ xr = x + (size_t)rr * L;
    float w[64], cur1[H];
    #pragma unroll
    for (int h = 0; h < H; ++h) cur1[h] = 0.f;
    int cntv = 0;
    #pragma unroll
    for (int i = 0; i < 64; ++i) w[i] = (i >= 24) ? xr[i - 24] : 0.f;
    #pragma unroll 1
    for (int s = 0; s < 12; ++s) {
        const int l0 = s * 15;
        #pragma unroll
        for (int j = 0; j < 15; ++j) {
            const int l = l0 + j;
            float yv = 0.f;
            #pragma unroll
            for (int k = 0; k < 50; ++k) yv = fmaf(w[j + k], filt[k], yv);
            const bool sb = yv > YTH;
            cntv += sb;
            const float sp = sb ? 1.f : 0.f;
            #pragma unroll
            for (int h = 0; h < H; ++h) cur1[h] = fmaf(sp, W1[h * L + l], cur1[h]);
        }
        #pragma unroll
        for (int i = 0; i < 49; ++i) w[i] = w[i + 15];
        #pragma unroll
        for (int d = 0; d < 15; ++d) {
            const int g = l0 + 40 + d;
            w[49 + d] = (g < L) ? xr[g] : 0.f;
        }
    }
    #pragma unroll
    for (int j = 0; j < 7; ++j) {
        const int l = 180 + j;
        float yv = 0.f;
        #pragma unroll
        for (int k = 0; k < 50; ++k) yv = fmaf(w[j + k], filt[k], yv);
        const bool sb = yv > YTH;
        cntv += sb;
        const float sp = sb ? 1.f : 0.f;
        #pragma unroll
        for (int h = 0; h < H; ++h) cur1[h] = fmaf(sp, W1[h * L + l], cur1[h]);
    }
    int wc = valid ? cntv : 0;
    #pragma unroll
    for (int off = 32; off; off >>= 1) wc += __shfl_down(wc, off);
    if ((threadIdx.x & 63) == 0) csh[threadIdx.x >> 6] = (unsigned)wc;
    __syncthreads();
    if (threadIdx.x == 0) part[blockIdx.x] = csh[0] + csh[1] + csh[2] + csh[3];
    float m1[H], m2[5];
    #pragma unroll
    for (int h = 0; h < H; ++h) m1[h] = 0.f;
    #pragma unroll
    for (int c = 0; c < 5; ++c) m2[c] = 0.f;
    #pragma unroll 1
    for (int t = 0; t < NST; ++t) {
        float c2[5] = {0, 0, 0, 0, 0};
        #pragma unroll
        for (int h = 0; h < H; ++h) {
            float m = fmaf(BETA, m1[h], cur1[h]);
            const float sp = (m > 1.f) ? 1.f : 0.f;
            m1[h] = m - sp;
            #pragma unroll
            for (int c = 0; c < 5; ++c) c2[c] = fmaf(sp, W2[c * H + h], c2[c]);
        }
        float* __restrict__ ot = out + ((size_t)t * B + rr) * 5;
        #pragma unroll
        for (int c = 0; c < 5; ++c) {
            float m = fmaf(BETA, m2[c], c2[c]);
            const float s2 = (m > 1.f) ? 1.f : 0.f;
            m2[c] = m - s2;
            if (valid) ot[c] = s2;
        }
    }
}

extern "C" void kernel_launch(void* const* d_in, const int* in_sizes, int n_in,
                              void* d_out, int out_size, void* d_ws, size_t ws_size,
                              hipStream_t stream)
{
    const float* x    = (const float*)d_in[0];
    const float* filt = (const float*)d_in[1];
    const float* W1   = (const float*)d_in[2];
    const float* W2   = (const float*)d_in[3];
    float* out        = (float*)d_out;
    const int B       = in_sizes[0] / L;          // 131072

    unsigned int* part    = (unsigned int*)d_ws;                   // NPART u32
    unsigned short* frags = (unsigned short*)((char*)d_ws + NPART * 4);
    const int total_sh    = FT_SH + W1A_SH + W2A_SH;               // 15424
    const size_t need     = (size_t)NPART * 4 + (size_t)total_sh * 2;

    if (ws_size >= need && (B % 64) == 0 && B / 64 <= NPART) {
        prep_frags<<<(total_sh + 255) / 256, 256, 0, stream>>>(filt, W1, W2, frags);
        snn_fused<<<B / 64, 256, 0, stream>>>(x, frags, out, part, B);
        finalize_count<<<1, 256, 0, stream>>>(part, B / 64, out, (size_t)NST * B * 5);
    } else {
        snn_fallback<<<(B + 255) / 256, 256, 0, stream>>>(x, filt, W1, W2, out, part, B);
        finalize_count<<<1, 256, 0, stream>>>(part, (B + 255) / 256, out, (size_t)NST * B * 5);
    }
}

// Round 13
// 55.402 us; speedup vs baseline: 1.2756x; 1.0078x over previous
//
#include <hip/hip_runtime.h>

// Fused SNN, single main kernel, 1 tile/wave, LDS-resident operands.
// MI355X (gfx950). R13: break the LIF serial chain:
//   - c2 via two INDEPENDENT MFMAs + packed add (was accumulator-chained).
//   - t-loop unroll 5 (25=5x5): step t+1's m1 pk_fma chains issue under
//     step t's MFMA/m2/store tail (cross-step ILP; R10 proved TLP is null).
// R12 carried: f32x2 packed LIF math, v_perm spike pack, phantom-pair skip,
// ballot+popc count, rotated-filter-table GEMM1, LDS W1/W2 frags.
//
// Per wave = ONE 16-row tile: GEMM1 (banded Toeplitz matmul from a rotated
// filter table in LDS, transposed so C-layout col = batch row) in nt-pairs ->
// threshold -> packed spike B-fragments (+count) -> GEMM2 (W1 frags in LDS)
// -> cur1^T in f32 registers -> 25-step LIF, W2 8-reg uniform A-fragment,
// 2 MFMAs/step, coalesced stores. Count: per-block partial; finalize sums.
//
// Contraction-slot bijection (GEMM2/GEMM3 B-side = previous C-layout):
//     k_slot(lk, jj, kt) = 4*lk + (jj&3) + 16*(2*kt + (jj>>2))

typedef float    f32x4 __attribute__((ext_vector_type(4)));
typedef float    f32x2 __attribute__((ext_vector_type(2)));
typedef short    s16x8 __attribute__((ext_vector_type(8)));

constexpr int L = 187;
constexpr int H = 50;
constexpr int NST = 25;
constexpr float BETA = 0.95f;
constexpr float YTH  = 0.25f;      // y*2 > 0.5  <=>  y > 0.25

constexpr int FT_STR = 264;               // ftab copy stride (shorts), 16B-mult
constexpr int FT_SH  = 8 * FT_STR;        // 2112 shorts = 4224 B
constexpr int W1A_SH = 4 * 6 * 64 * 8;    // 12288 shorts = 24 KB
constexpr int W2A_SH = 2 * 64 * 8;        // 1024 shorts = 2 KB
constexpr int NPART  = 4096;              // per-block count partials (max)

__device__ inline unsigned short f2bf(float f) {
    union { float f; unsigned u; } v; v.f = f;
    return (unsigned short)((v.u + 0x7FFFu + ((v.u >> 16) & 1u)) >> 16);  // RNE
}

// prep: ftab[r][m] = filt[m + r - 48] (0-padded), r<8, m<264, pre-strided;
// then W1A, W2A permuted fragments. Total 15424 shorts.
__global__ void __launch_bounds__(256) prep_frags(
    const float* __restrict__ filt, const float* __restrict__ W1,
    const float* __restrict__ W2, unsigned short* __restrict__ frags)
{
    int i = blockIdx.x * 256 + threadIdx.x;
    if (i < FT_SH) {
        int r = i / FT_STR, m = i - r * FT_STR;
        int idx = m + r - 48;
        frags[i] = (idx >= 0 && idx < 50) ? f2bf(filt[idx]) : (unsigned short)0;
    } else if (i < FT_SH + W1A_SH) {
        // A[h][l] permuted: h = 16*mt + lm, l = k_slot(lk,jj,kt)
        int i2 = i - FT_SH;
        int jj = i2 & 7, lane = (i2 >> 3) & 63, kt = (i2 >> 9) % 6, mt = i2 / (512 * 6);
        int lm = lane & 15, lk = lane >> 4;
        int h = 16 * mt + lm;
        int l = 4 * lk + (jj & 3) + 16 * (2 * kt + (jj >> 2));
        unsigned short v = 0;
        if (h < H && l < L) v = f2bf(W1[h * L + l]);
        frags[i] = v;
    } else if (i < FT_SH + W1A_SH + W2A_SH) {
        // A[c][h] permuted: c = lm, h = k_slot(lk,jj,kt)
        int i3 = i - FT_SH - W1A_SH;
        int jj = i3 & 7, lane = (i3 >> 3) & 63, kt = i3 >> 9;   // kt = 0,1
        int lm = lane & 15, lk = lane >> 4;
        int h = 4 * lk + (jj & 3) + 16 * (2 * kt + (jj >> 2));
        unsigned short v = 0;
        if (lm < 5 && h < H) v = f2bf(W2[lm * H + h]);
        frags[i] = v;
    }
}

// ======================= fused main kernel (1 tile / wave) ===================
__global__ void __launch_bounds__(256, 4) snn_fused(
    const float* __restrict__ x,
    const unsigned short* __restrict__ frags,
    float* __restrict__ out, unsigned int* __restrict__ part, int B)
{
    __shared__ __align__(16) unsigned short ftabL[FT_SH];
    __shared__ __align__(16) unsigned short W1L[W1A_SH];
    __shared__ __align__(16) unsigned short W2L[W2A_SH];
    __shared__ unsigned int csh[4];

    const int tid = threadIdx.x;
    const int wid = tid >> 6, lane = tid & 63;
    const int lm = lane & 15, lk = lane >> 4;
    const int row = blockIdx.x * 64 + wid * 16 + lm;

    // ---- stage wave-invariant operands to LDS (linear uint4 copies) ----
    {
        const uint4* g = (const uint4*)frags;     // 264 + 1536 + 128 chunks
        uint4* sF = (uint4*)ftabL;
        uint4* s1 = (uint4*)W1L;
        uint4* s2 = (uint4*)W2L;
        #pragma unroll 2
        for (int i = tid; i < 264; i += 256) sF[i] = g[i];
        #pragma unroll
        for (int i = tid; i < 1536; i += 256) s1[i] = g[264 + i];
        if (tid < 128) s2[tid] = g[264 + 1536 + tid];
    }
    __syncthreads();

    // xB: B-fragments of GEMM1 (canonical slots)
    s16x8 xB[6];
    {
        const float* __restrict__ xr = x + (size_t)row * L;
        #pragma unroll
        for (int kt = 0; kt < 6; ++kt) {
            const int k0 = 32 * kt + 8 * lk;
            s16x8 v;
            if (k0 + 8 <= L) {
                float t[8];
                __builtin_memcpy(t, xr + k0, 32);
                #pragma unroll
                for (int jj = 0; jj < 8; ++jj) v[jj] = (short)f2bf(t[jj]);
            } else {
                #pragma unroll
                for (int jj = 0; jj < 8; ++jj) {
                    int k = k0 + jj;
                    v[jj] = (short)f2bf((k < L) ? xr[k] : 0.f);
                }
            }
            xB[kt] = v;
        }
    }

    // GEMM1 by nt-pairs; A-fragments from the rotated filter table:
    // lane needs filt[d0 .. d0+7], d0 = 32kt + 8lk - 16nt - lm + 24.
    // D0 = d0+48; frag = ftabL[(D0&7)*FT_STR + (D0&~7) .. +7].
    const int dl = 8 * lk - lm + 72;              // +24 (toeplitz) +48 (table)
    unsigned int scnt = 0;                        // wave-uniform (ballot count)
    s16x8 spkB[6];
    {
        constexpr int lo[6] = {0, 0, 1, 2, 3, 4};
        constexpr int hi[6] = {1, 2, 3, 4, 5, 5};
        #pragma unroll
        for (int p = 0; p < 6; ++p) {
            f32x4 y0 = (f32x4){0, 0, 0, 0}, y1 = (f32x4){0, 0, 0, 0};
            #pragma unroll
            for (int kt = 0; kt < 6; ++kt) {
                if (kt >= lo[p] && kt <= hi[p]) {
                    const int D0a = dl + 32 * kt - 32 * p;      // nt = 2p
                    const int D0b = D0a - 16;                   // nt = 2p+1
                    s16x8 a0 = *(const s16x8*)&ftabL[(D0a & 7) * FT_STR + (D0a & ~7)];
                    s16x8 a1 = *(const s16x8*)&ftabL[(D0b & 7) * FT_STR + (D0b & ~7)];
                    y0 = __builtin_amdgcn_mfma_f32_16x16x32_bf16(a0, xB[kt], y0, 0, 0, 0);
                    y1 = __builtin_amdgcn_mfma_f32_16x16x32_bf16(a1, xB[kt], y1, 0, 0, 0);
                }
            }
            // pack pair -> spkB[p]; count via ballot (SALU); count-mask
            // phantom rows l>=187 (p=5, y1 side)
            union { unsigned w[4]; s16x8 v; } pk;
            #pragma unroll
            for (int w = 0; w < 4; ++w) {
                float va = (w < 2) ? y0[2 * w]     : y1[2 * (w - 2)];
                float vb = (w < 2) ? y0[2 * w + 1] : y1[2 * (w - 2) + 1];
                bool s0 = va > YTH, s1 = vb > YTH;
                bool c0 = s0, c1 = s1;
                if (p == 5 && w >= 2) {           // y1 rows: l = 176 + 4lk + j
                    c0 = s0 && ((4 * lk + 2 * (w - 2))     < 11);
                    c1 = s1 && ((4 * lk + 2 * (w - 2) + 1) < 11);
                }
                scnt += (unsigned)__popcll(__ballot(c0));
                scnt += (unsigned)__popcll(__ballot(c1));
                pk.w[w] = (s0 ? 0x3F80u : 0u) | (s1 ? 0x3F800000u : 0u);
            }
            spkB[p] = pk.v;
        }
    }
    // per-block partial count: scnt already wave-uniform
    if (lane == 0) csh[wid] = scnt;
    __syncthreads();
    if (tid == 0) part[blockIdx.x] = csh[0] + csh[1] + csh[2] + csh[3];

    // GEMM2: cur1^T[h][row] -> f32 registers (A from LDS)
    f32x4 cu[4];
    #pragma unroll
    for (int mt = 0; mt < 4; ++mt) cu[mt] = (f32x4){0, 0, 0, 0};
    #pragma unroll
    for (int mt = 0; mt < 4; ++mt)
        #pragma unroll
        for (int kt = 0; kt < 6; ++kt) {
            s16x8 a = *(const s16x8*)&W1L[((mt * 6 + kt) * 64 + lane) * 8];
            cu[mt] = __builtin_amdgcn_mfma_f32_16x16x32_bf16(a, spkB[kt], cu[mt], 0, 0, 0);
        }

    // W2 A-fragments (8 VGPRs, from LDS)
    s16x8 w2a[2];
    #pragma unroll
    for (int kt = 0; kt < 2; ++kt)
        w2a[kt] = *(const s16x8*)&W2L[(kt * 64 + lane) * 8];

    // -------- LIF: 25 steps, packed-f32 math, cross-step ILP --------
    // state as f32x2 pairs; pair (mt,hf) == s1b slot pw[2*mt+hf].
    f32x2 cup[4][2], m1p[4][2];
    #pragma unroll
    for (int mt = 0; mt < 4; ++mt) {
        cup[mt][0] = (f32x2){cu[mt][0], cu[mt][1]};
        cup[mt][1] = (f32x2){cu[mt][2], cu[mt][3]};
        m1p[mt][0] = (f32x2){0.f, 0.f};
        m1p[mt][1] = (f32x2){0.f, 0.f};
    }
    f32x4 m2 = (f32x4){0, 0, 0, 0};
    const f32x2 B2 = (f32x2){BETA, BETA};
    const f32x4 B4 = (f32x4){BETA, BETA, BETA, BETA};

    float* __restrict__ po = out + (size_t)row * 5;
    const size_t step = (size_t)B * 5;

    #pragma unroll 5
    for (int t = 0; t < NST; ++t) {
        unsigned pw[8];
        pw[7] = 0u;                                // mt3 hi: h>=50 for all lanes
        #pragma unroll
        for (int mt = 0; mt < 4; ++mt) {
            #pragma unroll
            for (int hf = 0; hf < 2; ++hf) {
                if (mt == 3 && hf == 1) continue;  // phantom pair
                f32x2 m = B2 * m1p[mt][hf] + cup[mt][hf];     // v_pk_fma_f32
                float s0 = (m[0] > 1.f) ? 1.f : 0.f;
                float s1 = (m[1] > 1.f) ? 1.f : 0.f;
                pw[2 * mt + hf] = __builtin_amdgcn_perm(
                    __float_as_uint(s1), __float_as_uint(s0), 0x07060302u);
                m1p[mt][hf] = m - (f32x2){s0, s1};            // v_pk_add_f32
            }
        }
        union { unsigned w[4]; s16x8 v; } u0, u1;
        u0.w[0] = pw[0]; u0.w[1] = pw[1]; u0.w[2] = pw[2]; u0.w[3] = pw[3];
        u1.w[0] = pw[4]; u1.w[1] = pw[5]; u1.w[2] = pw[6]; u1.w[3] = pw[7];
        // cur2^T via 2 INDEPENDENT MFMAs, combined with one packed add
        f32x4 c2a = (f32x4){0, 0, 0, 0}, c2b = (f32x4){0, 0, 0, 0};
        c2a = __builtin_amdgcn_mfma_f32_16x16x32_bf16(w2a[0], u0.v, c2a, 0, 0, 0);
        c2b = __builtin_amdgcn_mfma_f32_16x16x32_bf16(w2a[1], u1.v, c2b, 0, 0, 0);
        // m2 update + store spikes (lane holds c = 4*lk + j)
        f32x4 mm = B4 * m2 + (c2a + c2b);                     // pk_add + pk_fma
        f32x4 sv;
        #pragma unroll
        for (int j = 0; j < 4; ++j) sv[j] = (mm[j] > 1.f) ? 1.f : 0.f;
        m2 = mm - sv;                                         // 2x v_pk_add
        float* __restrict__ pt = po + (size_t)t * step;
        if (lk == 0) {
            __builtin_memcpy(pt, &sv, 16);        // c = 0..3
        } else if (lk == 1) {
            pt[4] = sv[0];                        // c = 4
        }
    }
}

// sum per-block partials -> out[off] = total * 25   (single block, no atomics)
__global__ void __launch_bounds__(256) finalize_count(
    const unsigned int* __restrict__ part, int n,
    float* __restrict__ out, size_t off)
{
    __shared__ unsigned int sh[4];
    unsigned int s = 0;
    for (int i = threadIdx.x; i < n; i += 256) s += part[i];
    #pragma unroll
    for (int o = 32; o; o >>= 1) s += __shfl_down(s, o);
    if ((threadIdx.x & 63) == 0) sh[threadIdx.x >> 6] = s;
    __syncthreads();
    if (threadIdx.x == 0) {
        unsigned int t = sh[0] + sh[1] + sh[2] + sh[3];
        out[off] = (float)((double)t * 25.0);
    }
}

// ============ fallback: scalar path (only if ws too small) ===================
__global__ void __launch_bounds__(256) snn_fallback(
    const float* __restrict__ x, const float* __restrict__ filt,
    const float* __restrict__ W1, const float* __restrict__ W2,
    float* __restrict__ out, unsigned int* __restrict__ part, int B)
{
    __shared__ unsigned int csh[4];
    const int row = blockIdx.x * 256 + threadIdx.x;
    const bool valid = row < B;
    const int rr = valid ? row : (B - 1);
    const float* __restrict__ xr = x + (size_t)rr * L;
    float w[64], cur1[H];
    #pragma unroll
    for (int h = 0; h < H; ++h) cur1[h] = 0.f;
    int cntv = 0;
    #pragma unroll
    for (int i = 0; i < 64; ++i) w[i] = (i >= 24) ? xr[i - 24] : 0.f;
    #pragma unroll 1
    for (int s = 0; s < 12; ++s) {
        const int l0 = s * 15;
        #pragma unroll
        for (int j = 0; j < 15; ++j) {
            const int l = l0 + j;
            float yv = 0.f;
            #pragma unroll
            for (int k = 0; k < 50; ++k) yv = fmaf(w[j + k], filt[k], yv);
            const bool sb = yv > YTH;
            cntv += sb;
            const float sp = sb ? 1.f : 0.f;
            #pragma unroll
            for (int h = 0; h < H; ++h) cur1[h] = fmaf(sp, W1[h * L + l], cur1[h]);
        }
        #pragma unroll
        for (int i = 0; i < 49; ++i) w[i] = w[i + 15];
        #pragma unroll
        for (int d = 0; d < 15; ++d) {
            const int g = l0 + 40 + d;
            w[49 + d] = (g < L) ? xr[g] : 0.f;
        }
    }
    #pragma unroll
    for (int j = 0; j < 7; ++j) {
        const int l = 180 + j;
        float yv = 0.f;
        #pragma unroll
        for (int k = 0; k < 50; ++k) yv = fmaf(w[j + k], filt[k], yv);
        const bool sb = yv > YTH;
        cntv += sb;
        const float sp = sb ? 1.f : 0.f;
        #pragma unroll
        for (int h = 0; h < H; ++h) cur1[h] = fmaf(sp, W1[h * L + l], cur1[h]);
    }
    int wc = valid ? cntv : 0;
    #pragma unroll
    for (int off = 32; off; off >>= 1) wc += __shfl_down(wc, off);
    if ((threadIdx.x & 63) == 0) csh[threadIdx.x >> 6] = (unsigned)wc;
    __syncthreads();
    if (threadIdx.x == 0) part[blockIdx.x] = csh[0] + csh[1] + csh[2] + csh[3];
    float m1[H], m2[5];
    #pragma unroll
    for (int h = 0; h < H; ++h) m1[h] = 0.f;
    #pragma unroll
    for (int c = 0; c < 5; ++c) m2[c] = 0.f;
    #pragma unroll 1
    for (int t = 0; t < NST; ++t) {
        float c2[5] = {0, 0, 0, 0, 0};
        #pragma unroll
        for (int h = 0; h < H; ++h) {
            float m = fmaf(BETA, m1[h], cur1[h]);
            const float sp = (m > 1.f) ? 1.f : 0.f;
            m1[h] = m - sp;
            #pragma unroll
            for (int c = 0; c < 5; ++c) c2[c] = fmaf(sp, W2[c * H + h], c2[c]);
        }
        float* __restrict__ ot = out + ((size_t)t * B + rr) * 5;
        #pragma unroll
        for (int c = 0; c < 5; ++c) {
            float m = fmaf(BETA, m2[c], c2[c]);
            const float s2 = (m > 1.f) ? 1.f : 0.f;
            m2[c] = m - s2;
            if (valid) ot[c] = s2;
        }
    }
}

extern "C" void kernel_launch(void* const* d_in, const int* in_sizes, int n_in,
                              void* d_out, int out_size, void* d_ws, size_t ws_size,
                              hipStream_t stream)
{
    const float* x    = (const float*)d_in[0];
    const float* filt = (const float*)d_in[1];
    const float* W1   = (const float*)d_in[2];
    const float* W2   = (const float*)d_in[3];
    float* out        = (float*)d_out;
    const int B       = in_sizes[0] / L;          // 131072

    unsigned int* part    = (unsigned int*)d_ws;                   // NPART u32
    unsigned short* frags = (unsigned short*)((char*)d_ws + NPART * 4);
    const int total_sh    = FT_SH + W1A_SH + W2A_SH;               // 15424
    const size_t need     = (size_t)NPART * 4 + (size_t)total_sh * 2;

    if (ws_size >= need && (B % 64) == 0 && B / 64 <= NPART) {
        prep_frags<<<(total_sh + 255) / 256, 256, 0, stream>>>(filt, W1, W2, frags);
        snn_fused<<<B / 64, 256, 0, stream>>>(x, frags, out, part, B);
        finalize_count<<<1, 256, 0, stream>>>(part, B / 64, out, (size_t)NST * B * 5);
    } else {
        snn_fallback<<<(B + 255) / 256, 256, 0, stream>>>(x, filt, W1, W2, out, part, B);
        finalize_count<<<1, 256, 0, stream>>>(part, (B + 255) / 256, out, (size_t)NST * B * 5);
    }
}